// Round 9
// baseline (173.661 us; speedup 1.0000x reference)
//
#include <hip/hip_runtime.h>
#include <hip/hip_bf16.h>

typedef __bf16 bf16_t;
typedef __attribute__((ext_vector_type(8))) __bf16 bf16x8;
typedef __attribute__((ext_vector_type(4))) __bf16 bf16x4;
typedef __attribute__((ext_vector_type(4))) float f32x4;

#define MFMA16(a, b, c) __builtin_amdgcn_mfma_f32_16x16x32_bf16((a), (b), (c), 0, 0, 0)

// ---------------------------------------------------------------------------
// Kernel 1: QKV projection (unchanged). Q pre-scaled by (1/sqrt(128))*log2e;
// V written transposed as [b][h][t].
// ---------------------------------------------------------------------------
__global__ __launch_bounds__(256, 3) void proj_qkv(
    const float* __restrict__ X,
    const float* __restrict__ W0, const float* __restrict__ W1, const float* __restrict__ W2,
    bf16_t* __restrict__ O0, bf16_t* __restrict__ O1, bf16_t* __restrict__ O2)
{
    __shared__ __align__(16) char As[128 * 128];
    __shared__ __align__(16) char Bs[128 * 128];

    const int tid = threadIdx.x;
    const int wid = tid >> 6;
    const int lane = tid & 63;
    const int l15 = lane & 15, l4 = lane >> 4;
    const int wr = wid >> 1, wc = wid & 1;
    const int m0 = blockIdx.x * 128;

    const float* W = (blockIdx.y == 0) ? W0 : (blockIdx.y == 1 ? W1 : W2);

    const int r0 = tid >> 4;
    const int kq = tid & 15;
    const int swz = ((r0 & 7) << 4);

    f32x4 acc[4][4] = {};
    float4 xr[8];

    #pragma unroll
    for (int i = 0; i < 8; ++i)
        xr[i] = *(const float4*)(X + (size_t)(m0 + r0 + i * 16) * 1024 + kq * 4);

    for (int ks = 0; ks < 16; ++ks) {
        const int kb = ks * 64;
        #pragma unroll
        for (int i = 0; i < 8; ++i) {
            const int r = r0 + i * 16;
            bf16x4 av; av[0] = (bf16_t)xr[i].x; av[1] = (bf16_t)xr[i].y;
            av[2] = (bf16_t)xr[i].z; av[3] = (bf16_t)xr[i].w;
            *(bf16x4*)(As + r * 128 + ((kq * 8) ^ swz)) = av;
        }
        #pragma unroll
        for (int i = 0; i < 8; ++i) {
            const int r = r0 + i * 16;
            float4 wa = *(const float4*)(W + (size_t)r * 1024 + kb + kq * 4);
            bf16x4 wv; wv[0] = (bf16_t)wa.x; wv[1] = (bf16_t)wa.y;
            wv[2] = (bf16_t)wa.z; wv[3] = (bf16_t)wa.w;
            *(bf16x4*)(Bs + r * 128 + ((kq * 8) ^ swz)) = wv;
        }
        __syncthreads();
        if (ks < 15) {
            #pragma unroll
            for (int i = 0; i < 8; ++i)
                xr[i] = *(const float4*)(X + (size_t)(m0 + r0 + i * 16) * 1024 + kb + 64 + kq * 4);
        }
        #pragma unroll
        for (int kk = 0; kk < 64; kk += 32) {
            const int kbyte = 2 * kk + 16 * l4;
            bf16x8 af[4], bfr[4];
            #pragma unroll
            for (int mi = 0; mi < 4; ++mi) {
                int r = wr * 64 + mi * 16 + l15;
                af[mi] = *(const bf16x8*)(As + r * 128 + (kbyte ^ ((r & 7) << 4)));
            }
            #pragma unroll
            for (int ni = 0; ni < 4; ++ni) {
                int r = wc * 64 + ni * 16 + l15;
                bfr[ni] = *(const bf16x8*)(Bs + r * 128 + (kbyte ^ ((r & 7) << 4)));
            }
            #pragma unroll
            for (int mi = 0; mi < 4; ++mi)
                #pragma unroll
                for (int ni = 0; ni < 4; ++ni)
                    acc[mi][ni] = MFMA16(af[mi], bfr[ni], acc[mi][ni]);
        }
        __syncthreads();
    }

    if (blockIdx.y < 2) {
        const float sc = (blockIdx.y == 0) ? 0.12751754816f : 1.0f;  // 1/sqrt(128)*log2e
        bf16_t* O = (blockIdx.y == 0) ? O0 : O1;
        #pragma unroll
        for (int mi = 0; mi < 4; ++mi)
            #pragma unroll
            for (int ni = 0; ni < 4; ++ni) {
                int row = m0 + wr * 64 + mi * 16 + l4 * 4;
                int col = wc * 64 + ni * 16 + l15;
                #pragma unroll
                for (int r = 0; r < 4; ++r)
                    O[(size_t)(row + r) * 128 + col] = (bf16_t)(acc[mi][ni][r] * sc);
            }
    } else {
        #pragma unroll
        for (int mi = 0; mi < 4; ++mi)
            #pragma unroll
            for (int ni = 0; ni < 4; ++ni) {
                int row0 = m0 + wr * 64 + mi * 16 + l4 * 4;
                int col = wc * 64 + ni * 16 + l15;
                int bb = row0 >> 12, t0 = row0 & 4095;
                bf16x4 pk;
                #pragma unroll
                for (int r = 0; r < 4; ++r) pk[r] = (bf16_t)acc[mi][ni][r];
                *(bf16x4*)(O2 + ((size_t)bb << 19) + (size_t)col * 4096 + t0) = pk;
            }
    }
}

// ---------------------------------------------------------------------------
// Kernel 2: causal flash attention — equal-length blocks, barrier-free loop.
// 512 blocks x 4 waves, atoms p=j then 127-j (129 32-kv tiles, identical for
// all blocks). Waves kv-split mod 4, fully autonomous: K AND V fragments read
// directly from L2-resident global into registers (prefetched one tile ahead);
// only P round-trips through LDS (conflict-free XOR swizzle). No barriers and
// no manual waitcnt in the main loop. Per-atom 4-state merge via LDS.
// ---------------------------------------------------------------------------
__global__ __launch_bounds__(256, 2) void attn_fwd(
    const bf16_t* __restrict__ Qb, const bf16_t* __restrict__ Kb,
    const bf16_t* __restrict__ Vtg, float* __restrict__ out, int Bn)
{
    // [0,64K): merge O-dump (4 x 16KB). [64K,72K): per-wave P (2KB each);
    // merge stats overlay at [64K..] after loop (P dead by then).
    __shared__ __align__(16) char lds[73728];

    const int tid = threadIdx.x, wid = tid >> 6, lane = tid & 63;
    const int l15 = lane & 15, l4 = lane >> 4;

    const int blk = blockIdx.x;
    const int b = blk % Bn;              // batch == XCD -> K/V L2-resident
    const int j = blk / Bn;              // 0..63

    const size_t base = (size_t)b * 4096 * 128;
    const size_t baseVT = (size_t)b << 19;

    char* Pw = lds + 65536 + wid * 2048;
    const int pswz = (l15 >> 1) & 3;     // 16B-chunk XOR swizzle key

    for (int seg = 0; seg < 2; ++seg) {
        const int p = seg ? (127 - j) : j;     // 32q atom index
        const int q0 = p << 5;
        const int nt = (p >= wid) ? ((p - wid) >> 2) + 1 : 0;  // my tiles: lt = wid+4i

        // Q fragments (B-operand): col q = q0+16qs+l15, k = 32kf+8l4+e.
        bf16x8 aq[2][4];
        #pragma unroll
        for (int qs = 0; qs < 2; ++qs)
            #pragma unroll
            for (int kf = 0; kf < 4; ++kf)
                aq[qs][kf] = *(const bf16x8*)(Qb + base
                    + (size_t)(q0 + 16 * qs + l15) * 128 + 32 * kf + 8 * l4);

        float mx[2] = {-1e30f, -1e30f}, lsum[2] = {0.f, 0.f};
        f32x4 o[2][8] = {};
        bf16x8 kreg[2][4];
        bf16x8 vreg[8];

        auto loadK = [&](int i) {
            const int kv0 = (wid + 4 * i) << 5;
            const bf16_t* kp = Kb + base + (size_t)(kv0 + l15) * 128 + 8 * l4;
            #pragma unroll
            for (int ni = 0; ni < 2; ++ni)
                #pragma unroll
                for (int kf = 0; kf < 4; ++kf)
                    kreg[ni][kf] = *(const bf16x8*)(kp + (size_t)ni * 2048 + kf * 32);
        };
        // V^T A-fragment straight from global: row h = 16mf+l15, kv = 8l4+e.
        auto loadV = [&](int i) {
            const int kv0 = (wid + 4 * i) << 5;
            const bf16_t* vp = Vtg + baseVT + (size_t)l15 * 4096 + kv0 + 8 * l4;
            #pragma unroll
            for (int mf = 0; mf < 8; ++mf)
                vreg[mf] = *(const bf16x8*)(vp + (size_t)(16 * mf) * 4096);
        };

        if (nt > 0) { loadK(0); loadV(0); }

        for (int i = 0; i < nt; ++i) {
            const int lt = wid + 4 * i;
            const int kv0 = lt << 5;

            // S^T = K * Q^T : D row = kv (16ni+4l4+r), col = q (l15).
            f32x4 sa[2][2];
            #pragma unroll
            for (int qs = 0; qs < 2; ++qs)
                #pragma unroll
                for (int ni = 0; ni < 2; ++ni) sa[qs][ni] = (f32x4){0.f, 0.f, 0.f, 0.f};
            __builtin_amdgcn_s_setprio(1);
            #pragma unroll
            for (int kf = 0; kf < 4; ++kf)
                #pragma unroll
                for (int ni = 0; ni < 2; ++ni) {
                    sa[0][ni] = MFMA16(kreg[ni][kf], aq[0][kf], sa[0][ni]);
                    sa[1][ni] = MFMA16(kreg[ni][kf], aq[1][kf], sa[1][ni]);
                }
            __builtin_amdgcn_s_setprio(0);

            if (i + 1 < nt) loadK(i + 1);   // prefetch, hidden under softmax+PV

            if (lt == p) {                  // only the diagonal tile masks
                #pragma unroll
                for (int qs = 0; qs < 2; ++qs) {
                    const int qg = q0 + 16 * qs + l15;
                    #pragma unroll
                    for (int ni = 0; ni < 2; ++ni)
                        #pragma unroll
                        for (int r = 0; r < 4; ++r)
                            if (kv0 + 16 * ni + 4 * l4 + r > qg) sa[qs][ni][r] = -1e30f;
                }
            }

            // Online softmax (base-2; stats lane-local per q, shfl over l4 bits).
            #pragma unroll
            for (int qs = 0; qs < 2; ++qs) {
                float tm = sa[qs][0][0];
                #pragma unroll
                for (int ni = 0; ni < 2; ++ni)
                    #pragma unroll
                    for (int r = 0; r < 4; ++r) tm = fmaxf(tm, sa[qs][ni][r]);
                tm = fmaxf(tm, __shfl_xor(tm, 16, 64));
                tm = fmaxf(tm, __shfl_xor(tm, 32, 64));
                if (__any(tm > mx[qs])) {        // exact defer: skip no-op rescale
                    const float mnew = fmaxf(mx[qs], tm);
                    const float c = exp2f(mx[qs] - mnew);
                    lsum[qs] *= c;
                    #pragma unroll
                    for (int mf = 0; mf < 8; ++mf) {
                        f32x4 t = o[qs][mf];
                        t[0] *= c; t[1] *= c; t[2] *= c; t[3] *= c;
                        o[qs][mf] = t;
                    }
                    mx[qs] = mnew;
                }
                float ss = 0.f;
                #pragma unroll
                for (int ni = 0; ni < 2; ++ni)
                    #pragma unroll
                    for (int r = 0; r < 4; ++r) {
                        float pv = exp2f(sa[qs][ni][r] - mx[qs]);
                        sa[qs][ni][r] = pv;
                        ss += pv;
                    }
                ss += __shfl_xor(ss, 16, 64);
                ss += __shfl_xor(ss, 32, 64);
                lsum[qs] += ss;
                // P write: row q = 16qs+l15 (64B rows); logical 16B chunk
                // x = 2ni+(l4>>1), physical chunk = x ^ pswz -> conflict-free.
                #pragma unroll
                for (int ni = 0; ni < 2; ++ni) {
                    bf16x4 pv;
                    pv[0] = (bf16_t)sa[qs][ni][0]; pv[1] = (bf16_t)sa[qs][ni][1];
                    pv[2] = (bf16_t)sa[qs][ni][2]; pv[3] = (bf16_t)sa[qs][ni][3];
                    *(bf16x4*)(Pw + (16 * qs + l15) * 64
                               + (((2 * ni + (l4 >> 1)) ^ pswz) << 4) + 8 * (l4 & 1)) = pv;
                }
            }

            // O^T += V^T * P^T : A = vreg (global), B = P (LDS, swizzled read).
            bf16x8 pa0 = *(const bf16x8*)(Pw + l15 * 64 + ((l4 ^ pswz) << 4));
            bf16x8 pa1 = *(const bf16x8*)(Pw + (16 + l15) * 64 + ((l4 ^ pswz) << 4));
            __builtin_amdgcn_s_setprio(1);
            #pragma unroll
            for (int mf = 0; mf < 8; ++mf) {
                o[0][mf] = MFMA16(vreg[mf], pa0, o[0][mf]);
                o[1][mf] = MFMA16(vreg[mf], pa1, o[1][mf]);
            }
            __builtin_amdgcn_s_setprio(0);

            if (i + 1 < nt) loadV(i + 1);   // WAR on vreg; lands across loop edge
        }

        // ---- per-atom merge of the 4 kv-split states ----
        __syncthreads();
        #pragma unroll
        for (int qs = 0; qs < 2; ++qs)
            #pragma unroll
            for (int mf = 0; mf < 8; ++mf)
                *(f32x4*)(lds + wid * 16384 + (qs * 8 + mf) * 1024 + lane * 16) = o[qs][mf];
        if (l4 == 0) {
            #pragma unroll
            for (int qs = 0; qs < 2; ++qs)
                *(float2*)(lds + 65536 + wid * 256 + (qs * 16 + l15) * 8)
                    = make_float2(mx[qs], lsum[qs]);
        }
        __syncthreads();
        #pragma unroll
        for (int qs = 0; qs < 2; ++qs) {
            float mw[4], lw[4];
            #pragma unroll
            for (int w = 0; w < 4; ++w) {
                float2 st = *(const float2*)(lds + 65536 + w * 256 + (qs * 16 + l15) * 8);
                mw[w] = st.x; lw[w] = st.y;
            }
            const float M = fmaxf(fmaxf(mw[0], mw[1]), fmaxf(mw[2], mw[3]));
            float cw[4], L = 0.f;
            #pragma unroll
            for (int w = 0; w < 4; ++w) { cw[w] = exp2f(mw[w] - M); L += lw[w] * cw[w]; }
            const float inv = 1.f / L;
            #pragma unroll
            for (int mm = 0; mm < 2; ++mm) {
                const int mf = 2 * wid + mm;    // this wave's h-slice
                f32x4 acc = (f32x4){0.f, 0.f, 0.f, 0.f};
                #pragma unroll
                for (int w = 0; w < 4; ++w) {
                    f32x4 v = *(const f32x4*)(lds + w * 16384 + (qs * 8 + mf) * 1024 + lane * 16);
                    #pragma unroll
                    for (int e = 0; e < 4; ++e) acc[e] += v[e] * cw[w];
                }
                #pragma unroll
                for (int e = 0; e < 4; ++e) acc[e] *= inv;
                float* op = out + ((size_t)b * 4096 + q0 + 16 * qs + l15) * 128 + 16 * mf + 4 * l4;
                *(f32x4*)op = acc;
            }
        }
        __syncthreads();   // P/stat region safe for next atom
    }
}

extern "C" void kernel_launch(void* const* d_in, const int* in_sizes, int n_in,
                              void* d_out, int out_size, void* d_ws, size_t ws_size,
                              hipStream_t stream) {
    const float* X  = (const float*)d_in[0];
    const float* Wq = (const float*)d_in[1];
    const float* Wk = (const float*)d_in[2];
    const float* Wv = (const float*)d_in[3];
    float* out = (float*)d_out;

    const int M = in_sizes[0] / 1024;      // B*T = 32768
    const int Bn = M / 4096;               // 8

    bf16_t* Qb  = (bf16_t*)d_ws;
    bf16_t* KbP = Qb + (size_t)M * 128;
    bf16_t* VtP = KbP + (size_t)M * 128;   // transposed: [b][128][4096]

    proj_qkv<<<dim3(M / 128, 3), 256, 0, stream>>>(X, Wq, Wk, Wv, Qb, KbP, VtP);
    attn_fwd<<<dim3(64 * Bn), 256, 0, stream>>>(Qb, KbP, VtP, out, Bn);
}

// Round 10
// 137.743 us; speedup vs baseline: 1.2608x; 1.2608x over previous
//
#include <hip/hip_runtime.h>
#include <hip/hip_bf16.h>

typedef __bf16 bf16_t;
typedef __attribute__((ext_vector_type(8))) __bf16 bf16x8;
typedef __attribute__((ext_vector_type(4))) __bf16 bf16x4;
typedef __attribute__((ext_vector_type(4))) float f32x4;

#define MFMA16(a, b, c) __builtin_amdgcn_mfma_f32_16x16x32_bf16((a), (b), (c), 0, 0, 0)

__device__ __forceinline__ void gload_lds16(const void* g, void* l) {
    __builtin_amdgcn_global_load_lds(
        (const __attribute__((address_space(1))) void*)g,
        (__attribute__((address_space(3))) void*)l, 16, 0, 0);
}

// ---------------------------------------------------------------------------
// Kernel 1: QKV projection (unchanged). Q pre-scaled by (1/sqrt(128))*log2e;
// V written transposed as [b][h][t].
// ---------------------------------------------------------------------------
__global__ __launch_bounds__(256, 3) void proj_qkv(
    const float* __restrict__ X,
    const float* __restrict__ W0, const float* __restrict__ W1, const float* __restrict__ W2,
    bf16_t* __restrict__ O0, bf16_t* __restrict__ O1, bf16_t* __restrict__ O2)
{
    __shared__ __align__(16) char As[128 * 128];
    __shared__ __align__(16) char Bs[128 * 128];

    const int tid = threadIdx.x;
    const int wid = tid >> 6;
    const int lane = tid & 63;
    const int l15 = lane & 15, l4 = lane >> 4;
    const int wr = wid >> 1, wc = wid & 1;
    const int m0 = blockIdx.x * 128;

    const float* W = (blockIdx.y == 0) ? W0 : (blockIdx.y == 1 ? W1 : W2);

    const int r0 = tid >> 4;
    const int kq = tid & 15;
    const int swz = ((r0 & 7) << 4);

    f32x4 acc[4][4] = {};
    float4 xr[8];

    #pragma unroll
    for (int i = 0; i < 8; ++i)
        xr[i] = *(const float4*)(X + (size_t)(m0 + r0 + i * 16) * 1024 + kq * 4);

    for (int ks = 0; ks < 16; ++ks) {
        const int kb = ks * 64;
        #pragma unroll
        for (int i = 0; i < 8; ++i) {
            const int r = r0 + i * 16;
            bf16x4 av; av[0] = (bf16_t)xr[i].x; av[1] = (bf16_t)xr[i].y;
            av[2] = (bf16_t)xr[i].z; av[3] = (bf16_t)xr[i].w;
            *(bf16x4*)(As + r * 128 + ((kq * 8) ^ swz)) = av;
        }
        #pragma unroll
        for (int i = 0; i < 8; ++i) {
            const int r = r0 + i * 16;
            float4 wa = *(const float4*)(W + (size_t)r * 1024 + kb + kq * 4);
            bf16x4 wv; wv[0] = (bf16_t)wa.x; wv[1] = (bf16_t)wa.y;
            wv[2] = (bf16_t)wa.z; wv[3] = (bf16_t)wa.w;
            *(bf16x4*)(Bs + r * 128 + ((kq * 8) ^ swz)) = wv;
        }
        __syncthreads();
        if (ks < 15) {
            #pragma unroll
            for (int i = 0; i < 8; ++i)
                xr[i] = *(const float4*)(X + (size_t)(m0 + r0 + i * 16) * 1024 + kb + 64 + kq * 4);
        }
        #pragma unroll
        for (int kk = 0; kk < 64; kk += 32) {
            const int kbyte = 2 * kk + 16 * l4;
            bf16x8 af[4], bfr[4];
            #pragma unroll
            for (int mi = 0; mi < 4; ++mi) {
                int r = wr * 64 + mi * 16 + l15;
                af[mi] = *(const bf16x8*)(As + r * 128 + (kbyte ^ ((r & 7) << 4)));
            }
            #pragma unroll
            for (int ni = 0; ni < 4; ++ni) {
                int r = wc * 64 + ni * 16 + l15;
                bfr[ni] = *(const bf16x8*)(Bs + r * 128 + (kbyte ^ ((r & 7) << 4)));
            }
            #pragma unroll
            for (int mi = 0; mi < 4; ++mi)
                #pragma unroll
                for (int ni = 0; ni < 4; ++ni)
                    acc[mi][ni] = MFMA16(af[mi], bfr[ni], acc[mi][ni]);
        }
        __syncthreads();
    }

    if (blockIdx.y < 2) {
        const float sc = (blockIdx.y == 0) ? 0.12751754816f : 1.0f;  // 1/sqrt(128)*log2e
        bf16_t* O = (blockIdx.y == 0) ? O0 : O1;
        #pragma unroll
        for (int mi = 0; mi < 4; ++mi)
            #pragma unroll
            for (int ni = 0; ni < 4; ++ni) {
                int row = m0 + wr * 64 + mi * 16 + l4 * 4;
                int col = wc * 64 + ni * 16 + l15;
                #pragma unroll
                for (int r = 0; r < 4; ++r)
                    O[(size_t)(row + r) * 128 + col] = (bf16_t)(acc[mi][ni][r] * sc);
            }
    } else {
        #pragma unroll
        for (int mi = 0; mi < 4; ++mi)
            #pragma unroll
            for (int ni = 0; ni < 4; ++ni) {
                int row0 = m0 + wr * 64 + mi * 16 + l4 * 4;
                int col = wc * 64 + ni * 16 + l15;
                int bb = row0 >> 12, t0 = row0 & 4095;
                bf16x4 pk;
                #pragma unroll
                for (int r = 0; r < 4; ++r) pk[r] = (bf16_t)acc[mi][ni][r];
                *(bf16x4*)(O2 + ((size_t)bb << 19) + (size_t)col * 4096 + t0) = pk;
            }
    }
}

// ---------------------------------------------------------------------------
// Kernel 2: causal flash attention — r8 structure (equal-length blocks, waves
// kv-split mod 4, V staged per-wave via global_load_lds dbuf, K from global,
// counted vmcnt sync, no main-loop barriers) + conflict-free LDS banking:
//   V: source pre-swizzle chunk^=((row>>1)&3), read chunk = l4^((l15>>1)&3)
//      -> every 8-lane b128 phase hits 8 distinct bank quads.
//   P: r9's chunk-XOR swizzle (verified, conflicts 10M -> 1M).
// ---------------------------------------------------------------------------
__global__ __launch_bounds__(256, 2) void attn_fwd(
    const bf16_t* __restrict__ Qb, const bf16_t* __restrict__ Kb,
    const bf16_t* __restrict__ Vtg, float* __restrict__ out, int Bn)
{
    // [0,64K): per-wave V dbuf (16KB each: 2 x 8KB [128h][64B kv-row]);
    //          merge phase reuses as 4 x 16KB O-dump.
    // [64K,72K): per-wave P (2KB); merge stats overlay after loop.
    __shared__ __align__(16) char lds[73728];

    const int tid = threadIdx.x, wid = tid >> 6, lane = tid & 63;
    const int l15 = lane & 15, l4 = lane >> 4;

    const int blk = blockIdx.x;
    const int b = blk % Bn;              // batch == XCD -> K/V L2-resident
    const int j = blk / Bn;              // 0..63

    const size_t base = (size_t)b * 4096 * 128;
    const size_t baseVT = (size_t)b << 19;

    char* Vw = lds + wid * 16384;
    char* Pw = lds + 65536 + wid * 2048;
    const int pswz = (l15 >> 1) & 3;     // P 16B-chunk XOR key
    const int vswz = (l15 >> 1) & 3;     // V 16B-chunk XOR key (read side)

    const int sh = lane >> 2;            // staging: row within 16-row chunk
    // V source pre-swizzle: physical chunk (lane&3) holds logical chunk
    // (lane&3)^((sh>>1)&3)  -> read with chunk = l4 ^ ((l15>>1)&3).
    const int skb = (((lane & 3) ^ ((sh >> 1) & 3))) * 8;

    for (int seg = 0; seg < 2; ++seg) {
        const int p = seg ? (127 - j) : j;     // 32q atom index
        const int q0 = p << 5;
        const int nt = (p >= wid) ? ((p - wid) >> 2) + 1 : 0;  // my tiles: lt = wid+4i

        // Q fragments (B-operand): col q = q0+16qs+l15, k = 32kf+8l4+e.
        bf16x8 aq[2][4];
        #pragma unroll
        for (int qs = 0; qs < 2; ++qs)
            #pragma unroll
            for (int kf = 0; kf < 4; ++kf)
                aq[qs][kf] = *(const bf16x8*)(Qb + base
                    + (size_t)(q0 + 16 * qs + l15) * 128 + 32 * kf + 8 * l4);

        float mx[2] = {-1e30f, -1e30f}, lsum[2] = {0.f, 0.f};
        f32x4 o[2][8] = {};
        bf16x8 kreg[2][4];

        auto stageV = [&](int i) {
            const int kv0 = (wid + 4 * i) << 5;
            char* dst = Vw + (i & 1) * 8192;
            #pragma unroll
            for (int c = 0; c < 8; ++c) {
                const bf16_t* src = Vtg + baseVT + (size_t)(16 * c + sh) * 4096 + kv0 + skb;
                gload_lds16(src, dst + c * 1024);
            }
        };
        auto loadK = [&](int i) {
            const int kv0 = (wid + 4 * i) << 5;
            const bf16_t* kp = Kb + base + (size_t)(kv0 + l15) * 128 + 8 * l4;
            #pragma unroll
            for (int ni = 0; ni < 2; ++ni)
                #pragma unroll
                for (int kf = 0; kf < 4; ++kf)
                    kreg[ni][kf] = *(const bf16x8*)(kp + (size_t)ni * 2048 + kf * 32);
        };

        if (nt > 0) { loadK(0); stageV(0); }

        for (int i = 0; i < nt; ++i) {
            const int lt = wid + 4 * i;
            const int kv0 = lt << 5;

            // S^T = K * Q^T : D row = kv (16ni+4l4+r), col = q (l15).
            f32x4 sa[2][2];
            #pragma unroll
            for (int qs = 0; qs < 2; ++qs)
                #pragma unroll
                for (int ni = 0; ni < 2; ++ni) sa[qs][ni] = (f32x4){0.f, 0.f, 0.f, 0.f};
            __builtin_amdgcn_s_setprio(1);
            #pragma unroll
            for (int kf = 0; kf < 4; ++kf)
                #pragma unroll
                for (int ni = 0; ni < 2; ++ni) {
                    sa[0][ni] = MFMA16(kreg[ni][kf], aq[0][kf], sa[0][ni]);
                    sa[1][ni] = MFMA16(kreg[ni][kf], aq[1][kf], sa[1][ni]);
                }
            __builtin_amdgcn_s_setprio(0);

            if (i + 1 < nt) loadK(i + 1);   // prefetch: hidden under softmax+PV

            if (lt == p) {                  // only the diagonal tile masks
                #pragma unroll
                for (int qs = 0; qs < 2; ++qs) {
                    const int qg = q0 + 16 * qs + l15;
                    #pragma unroll
                    for (int ni = 0; ni < 2; ++ni)
                        #pragma unroll
                        for (int r = 0; r < 4; ++r)
                            if (kv0 + 16 * ni + 4 * l4 + r > qg) sa[qs][ni][r] = -1e30f;
                }
            }

            // Online softmax (base-2; stats lane-local per q, shfl over l4 bits).
            #pragma unroll
            for (int qs = 0; qs < 2; ++qs) {
                float tm = sa[qs][0][0];
                #pragma unroll
                for (int ni = 0; ni < 2; ++ni)
                    #pragma unroll
                    for (int r = 0; r < 4; ++r) tm = fmaxf(tm, sa[qs][ni][r]);
                tm = fmaxf(tm, __shfl_xor(tm, 16, 64));
                tm = fmaxf(tm, __shfl_xor(tm, 32, 64));
                if (__any(tm > mx[qs])) {        // exact defer: skip no-op rescale
                    const float mnew = fmaxf(mx[qs], tm);
                    const float c = exp2f(mx[qs] - mnew);
                    lsum[qs] *= c;
                    #pragma unroll
                    for (int mf = 0; mf < 8; ++mf) {
                        f32x4 t = o[qs][mf];
                        t[0] *= c; t[1] *= c; t[2] *= c; t[3] *= c;
                        o[qs][mf] = t;
                    }
                    mx[qs] = mnew;
                }
                float ss = 0.f;
                #pragma unroll
                for (int ni = 0; ni < 2; ++ni)
                    #pragma unroll
                    for (int r = 0; r < 4; ++r) {
                        float pv = exp2f(sa[qs][ni][r] - mx[qs]);
                        sa[qs][ni][r] = pv;
                        ss += pv;
                    }
                ss += __shfl_xor(ss, 16, 64);
                ss += __shfl_xor(ss, 32, 64);
                lsum[qs] += ss;
                // P write: row q = 16qs+l15 (64B rows); logical 16B chunk
                // x = 2ni+(l4>>1), physical = x ^ pswz (conflict-free).
                #pragma unroll
                for (int ni = 0; ni < 2; ++ni) {
                    bf16x4 pv;
                    pv[0] = (bf16_t)sa[qs][ni][0]; pv[1] = (bf16_t)sa[qs][ni][1];
                    pv[2] = (bf16_t)sa[qs][ni][2]; pv[3] = (bf16_t)sa[qs][ni][3];
                    *(bf16x4*)(Pw + (16 * qs + l15) * 64
                               + (((2 * ni + (l4 >> 1)) ^ pswz) << 4) + 8 * (l4 & 1)) = pv;
                }
            }

            // V(i) readiness: keep 8 newest (K prefetch), drain stageV(i).
            __builtin_amdgcn_sched_barrier(0);
            asm volatile("s_waitcnt vmcnt(8)" ::: "memory");
            __builtin_amdgcn_sched_barrier(0);

            // O^T += V^T * P^T : D row = h (16mf+4l4+r), col = q (l15).
            char* Vbuf = Vw + (i & 1) * 8192;
            bf16x8 pa0 = *(const bf16x8*)(Pw + l15 * 64 + ((l4 ^ pswz) << 4));
            bf16x8 pa1 = *(const bf16x8*)(Pw + (16 + l15) * 64 + ((l4 ^ pswz) << 4));
            __builtin_amdgcn_s_setprio(1);
            #pragma unroll
            for (int mf = 0; mf < 8; ++mf) {
                bf16x8 av = *(const bf16x8*)(Vbuf + (16 * mf + l15) * 64
                                             + ((l4 ^ vswz) << 4));
                o[0][mf] = MFMA16(av, pa0, o[0][mf]);
                o[1][mf] = MFMA16(av, pa1, o[1][mf]);
            }
            __builtin_amdgcn_s_setprio(0);

            if (i + 1 < nt) stageV(i + 1);  // lands across the loop-back edge
        }

        // ---- per-atom merge of the 4 kv-split states ----
        asm volatile("s_waitcnt vmcnt(0)" ::: "memory");
        __syncthreads();
        #pragma unroll
        for (int qs = 0; qs < 2; ++qs)
            #pragma unroll
            for (int mf = 0; mf < 8; ++mf)
                *(f32x4*)(lds + wid * 16384 + (qs * 8 + mf) * 1024 + lane * 16) = o[qs][mf];
        if (l4 == 0) {
            #pragma unroll
            for (int qs = 0; qs < 2; ++qs)
                *(float2*)(lds + 65536 + wid * 256 + (qs * 16 + l15) * 8)
                    = make_float2(mx[qs], lsum[qs]);
        }
        __syncthreads();
        #pragma unroll
        for (int qs = 0; qs < 2; ++qs) {
            float mw[4], lw[4];
            #pragma unroll
            for (int w = 0; w < 4; ++w) {
                float2 st = *(const float2*)(lds + 65536 + w * 256 + (qs * 16 + l15) * 8);
                mw[w] = st.x; lw[w] = st.y;
            }
            const float M = fmaxf(fmaxf(mw[0], mw[1]), fmaxf(mw[2], mw[3]));
            float cw[4], L = 0.f;
            #pragma unroll
            for (int w = 0; w < 4; ++w) { cw[w] = exp2f(mw[w] - M); L += lw[w] * cw[w]; }
            const float inv = 1.f / L;
            #pragma unroll
            for (int mm = 0; mm < 2; ++mm) {
                const int mf = 2 * wid + mm;    // this wave's h-slice
                f32x4 acc = (f32x4){0.f, 0.f, 0.f, 0.f};
                #pragma unroll
                for (int w = 0; w < 4; ++w) {
                    f32x4 v = *(const f32x4*)(lds + w * 16384 + (qs * 8 + mf) * 1024 + lane * 16);
                    #pragma unroll
                    for (int e = 0; e < 4; ++e) acc[e] += v[e] * cw[w];
                }
                #pragma unroll
                for (int e = 0; e < 4; ++e) acc[e] *= inv;
                float* op = out + ((size_t)b * 4096 + q0 + 16 * qs + l15) * 128 + 16 * mf + 4 * l4;
                *(f32x4*)op = acc;
            }
        }
        __syncthreads();   // V/P regions safe for next atom
    }
}

extern "C" void kernel_launch(void* const* d_in, const int* in_sizes, int n_in,
                              void* d_out, int out_size, void* d_ws, size_t ws_size,
                              hipStream_t stream) {
    const float* X  = (const float*)d_in[0];
    const float* Wq = (const float*)d_in[1];
    const float* Wk = (const float*)d_in[2];
    const float* Wv = (const float*)d_in[3];
    float* out = (float*)d_out;

    const int M = in_sizes[0] / 1024;      // B*T = 32768
    const int Bn = M / 4096;               // 8

    bf16_t* Qb  = (bf16_t*)d_ws;
    bf16_t* KbP = Qb + (size_t)M * 128;
    bf16_t* VtP = KbP + (size_t)M * 128;   // transposed: [b][128][4096]

    proj_qkv<<<dim3(M / 128, 3), 256, 0, stream>>>(X, Wq, Wk, Wv, Qb, KbP, VtP);
    attn_fwd<<<dim3(64 * Bn), 256, 0, stream>>>(Qb, KbP, VtP, out, Bn);
}

// Round 11
// 137.434 us; speedup vs baseline: 1.2636x; 1.0022x over previous
//
#include <hip/hip_runtime.h>
#include <hip/hip_bf16.h>

typedef __bf16 bf16_t;
typedef __attribute__((ext_vector_type(8))) __bf16 bf16x8;
typedef __attribute__((ext_vector_type(4))) __bf16 bf16x4;
typedef __attribute__((ext_vector_type(4))) float f32x4;

#define MFMA16(a, b, c) __builtin_amdgcn_mfma_f32_16x16x32_bf16((a), (b), (c), 0, 0, 0)

__device__ __forceinline__ void gload_lds16(const void* g, void* l) {
    __builtin_amdgcn_global_load_lds(
        (const __attribute__((address_space(1))) void*)g,
        (__attribute__((address_space(3))) void*)l, 16, 0, 0);
}

// ---------------------------------------------------------------------------
// Kernel 1: QKV projection (unchanged). Q pre-scaled by (1/sqrt(128))*log2e;
// V written transposed as [b][h][t].
// ---------------------------------------------------------------------------
__global__ __launch_bounds__(256, 3) void proj_qkv(
    const float* __restrict__ X,
    const float* __restrict__ W0, const float* __restrict__ W1, const float* __restrict__ W2,
    bf16_t* __restrict__ O0, bf16_t* __restrict__ O1, bf16_t* __restrict__ O2)
{
    __shared__ __align__(16) char As[128 * 128];
    __shared__ __align__(16) char Bs[128 * 128];

    const int tid = threadIdx.x;
    const int wid = tid >> 6;
    const int lane = tid & 63;
    const int l15 = lane & 15, l4 = lane >> 4;
    const int wr = wid >> 1, wc = wid & 1;
    const int m0 = blockIdx.x * 128;

    const float* W = (blockIdx.y == 0) ? W0 : (blockIdx.y == 1 ? W1 : W2);

    const int r0 = tid >> 4;
    const int kq = tid & 15;
    const int swz = ((r0 & 7) << 4);

    f32x4 acc[4][4] = {};
    float4 xr[8];

    #pragma unroll
    for (int i = 0; i < 8; ++i)
        xr[i] = *(const float4*)(X + (size_t)(m0 + r0 + i * 16) * 1024 + kq * 4);

    for (int ks = 0; ks < 16; ++ks) {
        const int kb = ks * 64;
        #pragma unroll
        for (int i = 0; i < 8; ++i) {
            const int r = r0 + i * 16;
            bf16x4 av; av[0] = (bf16_t)xr[i].x; av[1] = (bf16_t)xr[i].y;
            av[2] = (bf16_t)xr[i].z; av[3] = (bf16_t)xr[i].w;
            *(bf16x4*)(As + r * 128 + ((kq * 8) ^ swz)) = av;
        }
        #pragma unroll
        for (int i = 0; i < 8; ++i) {
            const int r = r0 + i * 16;
            float4 wa = *(const float4*)(W + (size_t)r * 1024 + kb + kq * 4);
            bf16x4 wv; wv[0] = (bf16_t)wa.x; wv[1] = (bf16_t)wa.y;
            wv[2] = (bf16_t)wa.z; wv[3] = (bf16_t)wa.w;
            *(bf16x4*)(Bs + r * 128 + ((kq * 8) ^ swz)) = wv;
        }
        __syncthreads();
        if (ks < 15) {
            #pragma unroll
            for (int i = 0; i < 8; ++i)
                xr[i] = *(const float4*)(X + (size_t)(m0 + r0 + i * 16) * 1024 + kb + 64 + kq * 4);
        }
        #pragma unroll
        for (int kk = 0; kk < 64; kk += 32) {
            const int kbyte = 2 * kk + 16 * l4;
            bf16x8 af[4], bfr[4];
            #pragma unroll
            for (int mi = 0; mi < 4; ++mi) {
                int r = wr * 64 + mi * 16 + l15;
                af[mi] = *(const bf16x8*)(As + r * 128 + (kbyte ^ ((r & 7) << 4)));
            }
            #pragma unroll
            for (int ni = 0; ni < 4; ++ni) {
                int r = wc * 64 + ni * 16 + l15;
                bfr[ni] = *(const bf16x8*)(Bs + r * 128 + (kbyte ^ ((r & 7) << 4)));
            }
            #pragma unroll
            for (int mi = 0; mi < 4; ++mi)
                #pragma unroll
                for (int ni = 0; ni < 4; ++ni)
                    acc[mi][ni] = MFMA16(af[mi], bfr[ni], acc[mi][ni]);
        }
        __syncthreads();
    }

    if (blockIdx.y < 2) {
        const float sc = (blockIdx.y == 0) ? 0.12751754816f : 1.0f;  // 1/sqrt(128)*log2e
        bf16_t* O = (blockIdx.y == 0) ? O0 : O1;
        #pragma unroll
        for (int mi = 0; mi < 4; ++mi)
            #pragma unroll
            for (int ni = 0; ni < 4; ++ni) {
                int row = m0 + wr * 64 + mi * 16 + l4 * 4;
                int col = wc * 64 + ni * 16 + l15;
                #pragma unroll
                for (int r = 0; r < 4; ++r)
                    O[(size_t)(row + r) * 128 + col] = (bf16_t)(acc[mi][ni][r] * sc);
            }
    } else {
        #pragma unroll
        for (int mi = 0; mi < 4; ++mi)
            #pragma unroll
            for (int ni = 0; ni < 4; ++ni) {
                int row0 = m0 + wr * 64 + mi * 16 + l4 * 4;
                int col = wc * 64 + ni * 16 + l15;
                int bb = row0 >> 12, t0 = row0 & 4095;
                bf16x4 pk;
                #pragma unroll
                for (int r = 0; r < 4; ++r) pk[r] = (bf16_t)acc[mi][ni][r];
                *(bf16x4*)(O2 + ((size_t)bb << 19) + (size_t)col * 4096 + t0) = pk;
            }
    }
}

// ---------------------------------------------------------------------------
// Kernel 2: causal flash attention — r10 structure (equal-length blocks,
// waves kv-split mod 4, per-wave V dbuf via global_load_lds, K from global,
// counted vmcnt, conflict-free V/P swizzles) + critical-path softmax:
//   * denominator via ones-row MFMA (no cross-lane sum, off critical path)
//   * threshold-deferred max THR=8 (base-2): steady-state tiles do NO
//     cross-lane shuffles at all; trigger uses lane-local max + __any.
// ---------------------------------------------------------------------------
__global__ __launch_bounds__(256, 2) void attn_fwd(
    const bf16_t* __restrict__ Qb, const bf16_t* __restrict__ Kb,
    const bf16_t* __restrict__ Vtg, float* __restrict__ out, int Bn)
{
    // [0,64K): per-wave V dbuf (16KB each: 2 x 8KB [128h][64B kv-row]);
    //          merge phase reuses as 4 x 16KB O-dump.
    // [64K,72K): per-wave P (2KB); merge stats overlay after loop.
    __shared__ __align__(16) char lds[73728];

    const int tid = threadIdx.x, wid = tid >> 6, lane = tid & 63;
    const int l15 = lane & 15, l4 = lane >> 4;

    const int blk = blockIdx.x;
    const int b = blk % Bn;              // batch == XCD -> K/V L2-resident
    const int j = blk / Bn;              // 0..63

    const size_t base = (size_t)b * 4096 * 128;
    const size_t baseVT = (size_t)b << 19;

    char* Vw = lds + wid * 16384;
    char* Pw = lds + 65536 + wid * 2048;
    const int pswz = (l15 >> 1) & 3;     // P 16B-chunk XOR key
    const int vswz = (l15 >> 1) & 3;     // V 16B-chunk XOR key (read side)

    const int sh = lane >> 2;            // staging: row within 16-row chunk
    const int skb = (((lane & 3) ^ ((sh >> 1) & 3))) * 8;  // V src pre-swizzle

    // Constant all-ones A fragment: row-sum MFMA for the softmax denominator.
    bf16x8 aones;
    #pragma unroll
    for (int e = 0; e < 8; ++e) aones[e] = (bf16_t)1.0f;

    for (int seg = 0; seg < 2; ++seg) {
        const int p = seg ? (127 - j) : j;     // 32q atom index
        const int q0 = p << 5;
        const int nt = (p >= wid) ? ((p - wid) >> 2) + 1 : 0;  // my tiles: lt = wid+4i

        // Q fragments (B-operand): col q = q0+16qs+l15, k = 32kf+8l4+e.
        bf16x8 aq[2][4];
        #pragma unroll
        for (int qs = 0; qs < 2; ++qs)
            #pragma unroll
            for (int kf = 0; kf < 4; ++kf)
                aq[qs][kf] = *(const bf16x8*)(Qb + base
                    + (size_t)(q0 + 16 * qs + l15) * 128 + 32 * kf + 8 * l4);

        float mx[2] = {-1e30f, -1e30f};
        f32x4 ls_acc[2] = {};              // denominator accumulator (ones-MFMA)
        f32x4 o[2][8] = {};
        bf16x8 kreg[2][4];

        auto stageV = [&](int i) {
            const int kv0 = (wid + 4 * i) << 5;
            char* dst = Vw + (i & 1) * 8192;
            #pragma unroll
            for (int c = 0; c < 8; ++c) {
                const bf16_t* src = Vtg + baseVT + (size_t)(16 * c + sh) * 4096 + kv0 + skb;
                gload_lds16(src, dst + c * 1024);
            }
        };
        auto loadK = [&](int i) {
            const int kv0 = (wid + 4 * i) << 5;
            const bf16_t* kp = Kb + base + (size_t)(kv0 + l15) * 128 + 8 * l4;
            #pragma unroll
            for (int ni = 0; ni < 2; ++ni)
                #pragma unroll
                for (int kf = 0; kf < 4; ++kf)
                    kreg[ni][kf] = *(const bf16x8*)(kp + (size_t)ni * 2048 + kf * 32);
        };

        if (nt > 0) { loadK(0); stageV(0); }

        for (int i = 0; i < nt; ++i) {
            const int lt = wid + 4 * i;
            const int kv0 = lt << 5;

            // S^T = K * Q^T : D row = kv (16ni+4l4+r), col = q (l15).
            f32x4 sa[2][2];
            #pragma unroll
            for (int qs = 0; qs < 2; ++qs)
                #pragma unroll
                for (int ni = 0; ni < 2; ++ni) sa[qs][ni] = (f32x4){0.f, 0.f, 0.f, 0.f};
            __builtin_amdgcn_s_setprio(1);
            #pragma unroll
            for (int kf = 0; kf < 4; ++kf)
                #pragma unroll
                for (int ni = 0; ni < 2; ++ni) {
                    sa[0][ni] = MFMA16(kreg[ni][kf], aq[0][kf], sa[0][ni]);
                    sa[1][ni] = MFMA16(kreg[ni][kf], aq[1][kf], sa[1][ni]);
                }
            __builtin_amdgcn_s_setprio(0);

            if (i + 1 < nt) loadK(i + 1);   // prefetch: hidden under softmax+PV

            if (lt == p) {                  // only the diagonal tile masks
                #pragma unroll
                for (int qs = 0; qs < 2; ++qs) {
                    const int qg = q0 + 16 * qs + l15;
                    #pragma unroll
                    for (int ni = 0; ni < 2; ++ni)
                        #pragma unroll
                        for (int r = 0; r < 4; ++r)
                            if (kv0 + 16 * ni + 4 * l4 + r > qg) sa[qs][ni][r] = -1e30f;
                }
            }

            // Softmax, base-2, threshold-deferred max (THR=8 -> P <= 256).
            #pragma unroll
            for (int qs = 0; qs < 2; ++qs) {
                float tm = fmaxf(fmaxf(fmaxf(sa[qs][0][0], sa[qs][0][1]),
                                       fmaxf(sa[qs][0][2], sa[qs][0][3])),
                                 fmaxf(fmaxf(sa[qs][1][0], sa[qs][1][1]),
                                       fmaxf(sa[qs][1][2], sa[qs][1][3])));
                if (__any(tm > mx[qs] + 8.0f)) {   // rare: full reduce + rescale
                    tm = fmaxf(tm, __shfl_xor(tm, 16, 64));
                    tm = fmaxf(tm, __shfl_xor(tm, 32, 64));
                    const float mnew = fmaxf(mx[qs], tm);
                    const float c = exp2f(mx[qs] - mnew);
                    f32x4 lt4 = ls_acc[qs];
                    lt4[0] *= c; lt4[1] *= c; lt4[2] *= c; lt4[3] *= c;
                    ls_acc[qs] = lt4;
                    #pragma unroll
                    for (int mf = 0; mf < 8; ++mf) {
                        f32x4 t = o[qs][mf];
                        t[0] *= c; t[1] *= c; t[2] *= c; t[3] *= c;
                        o[qs][mf] = t;
                    }
                    mx[qs] = mnew;
                }
                // P = exp2(S - mx); bounded by 2^8. No sum here (ones-MFMA).
                #pragma unroll
                for (int ni = 0; ni < 2; ++ni) {
                    bf16x4 pv;
                    #pragma unroll
                    for (int r = 0; r < 4; ++r)
                        pv[r] = (bf16_t)exp2f(sa[qs][ni][r] - mx[qs]);
                    *(bf16x4*)(Pw + (16 * qs + l15) * 64
                               + (((2 * ni + (l4 >> 1)) ^ pswz) << 4) + 8 * (l4 & 1)) = pv;
                }
            }

            // V(i) readiness: keep 8 newest (K prefetch), drain stageV(i).
            __builtin_amdgcn_sched_barrier(0);
            asm volatile("s_waitcnt vmcnt(8)" ::: "memory");
            __builtin_amdgcn_sched_barrier(0);

            // O^T += V^T * P^T, plus denominator row: ls += ones * P.
            char* Vbuf = Vw + (i & 1) * 8192;
            bf16x8 pa0 = *(const bf16x8*)(Pw + l15 * 64 + ((l4 ^ pswz) << 4));
            bf16x8 pa1 = *(const bf16x8*)(Pw + (16 + l15) * 64 + ((l4 ^ pswz) << 4));
            __builtin_amdgcn_s_setprio(1);
            ls_acc[0] = MFMA16(aones, pa0, ls_acc[0]);
            ls_acc[1] = MFMA16(aones, pa1, ls_acc[1]);
            #pragma unroll
            for (int mf = 0; mf < 8; ++mf) {
                bf16x8 av = *(const bf16x8*)(Vbuf + (16 * mf + l15) * 64
                                             + ((l4 ^ vswz) << 4));
                o[0][mf] = MFMA16(av, pa0, o[0][mf]);
                o[1][mf] = MFMA16(av, pa1, o[1][mf]);
            }
            __builtin_amdgcn_s_setprio(0);

            if (i + 1 < nt) stageV(i + 1);  // lands across the loop-back edge
        }

        // ---- per-atom merge of the 4 kv-split states ----
        asm volatile("s_waitcnt vmcnt(0)" ::: "memory");
        __syncthreads();
        #pragma unroll
        for (int qs = 0; qs < 2; ++qs)
            #pragma unroll
            for (int mf = 0; mf < 8; ++mf)
                *(f32x4*)(lds + wid * 16384 + (qs * 8 + mf) * 1024 + lane * 16) = o[qs][mf];
        if (l4 == 0) {
            #pragma unroll
            for (int qs = 0; qs < 2; ++qs)
                *(float2*)(lds + 65536 + wid * 256 + (qs * 16 + l15) * 8)
                    = make_float2(mx[qs], ls_acc[qs][0]);
        }
        __syncthreads();
        #pragma unroll
        for (int qs = 0; qs < 2; ++qs) {
            float mw[4], lw[4];
            #pragma unroll
            for (int w = 0; w < 4; ++w) {
                float2 st = *(const float2*)(lds + 65536 + w * 256 + (qs * 16 + l15) * 8);
                mw[w] = st.x; lw[w] = st.y;
            }
            const float M = fmaxf(fmaxf(mw[0], mw[1]), fmaxf(mw[2], mw[3]));
            float cw[4], L = 0.f;
            #pragma unroll
            for (int w = 0; w < 4; ++w) { cw[w] = exp2f(mw[w] - M); L += lw[w] * cw[w]; }
            const float inv = 1.f / L;
            #pragma unroll
            for (int mm = 0; mm < 2; ++mm) {
                const int mf = 2 * wid + mm;    // this wave's h-slice
                f32x4 acc = (f32x4){0.f, 0.f, 0.f, 0.f};
                #pragma unroll
                for (int w = 0; w < 4; ++w) {
                    f32x4 v = *(const f32x4*)(lds + w * 16384 + (qs * 8 + mf) * 1024 + lane * 16);
                    #pragma unroll
                    for (int e = 0; e < 4; ++e) acc[e] += v[e] * cw[w];
                }
                #pragma unroll
                for (int e = 0; e < 4; ++e) acc[e] *= inv;
                float* op = out + ((size_t)b * 4096 + q0 + 16 * qs + l15) * 128 + 16 * mf + 4 * l4;
                *(f32x4*)op = acc;
            }
        }
        __syncthreads();   // V/P regions safe for next atom
    }
}

extern "C" void kernel_launch(void* const* d_in, const int* in_sizes, int n_in,
                              void* d_out, int out_size, void* d_ws, size_t ws_size,
                              hipStream_t stream) {
    const float* X  = (const float*)d_in[0];
    const float* Wq = (const float*)d_in[1];
    const float* Wk = (const float*)d_in[2];
    const float* Wv = (const float*)d_in[3];
    float* out = (float*)d_out;

    const int M = in_sizes[0] / 1024;      // B*T = 32768
    const int Bn = M / 4096;               // 8

    bf16_t* Qb  = (bf16_t*)d_ws;
    bf16_t* KbP = Qb + (size_t)M * 128;
    bf16_t* VtP = KbP + (size_t)M * 128;   // transposed: [b][128][4096]

    proj_qkv<<<dim3(M / 128, 3), 256, 0, stream>>>(X, Wq, Wk, Wv, Qb, KbP, VtP);
    attn_fwd<<<dim3(64 * Bn), 256, 0, stream>>>(Qb, KbP, VtP, out, Bn);
}